// Round 10
// baseline (853.041 us; speedup 1.0000x reference)
//
#include <hip/hip_runtime.h>
#include <hip/hip_bf16.h>

#define S_LEN 2048
#define HID_DIM 4096
#define NH 32
#define HD 128
#define NQKV 12288

typedef _Float16 half2v __attribute__((ext_vector_type(2)));
typedef _Float16 half4v __attribute__((ext_vector_type(4)));
typedef _Float16 half8v __attribute__((ext_vector_type(8)));
typedef float f32x4 __attribute__((ext_vector_type(4)));

typedef const __attribute__((address_space(1))) unsigned int* gas_u32;
typedef __attribute__((address_space(3))) unsigned int* las_u32;

__device__ inline void g2lds16(const _Float16* g, _Float16* l) {
  __builtin_amdgcn_global_load_lds((gas_u32)g, (las_u32)l, 16, 0, 0);
}

// ---------------- dequant W[K,N] int32 -> Wt[N,K] f16 (transposed) ----------------
__global__ __launch_bounds__(256) void dequant_w(const int* __restrict__ W,
                                                 const float* __restrict__ scal,
                                                 const float* __restrict__ zer,
                                                 _Float16* __restrict__ Wt, int K, int N) {
  __shared__ _Float16 lT[64 * 84];  // [n][k]
  const int k0 = blockIdx.y * 64, n0 = blockIdx.x * 64;
  const int tid = threadIdx.x, c = tid & 63, rp = tid >> 6;
  const int g = k0 >> 7;  // 64 | 128 -> group uniform over tile
  const float sc = scal[(size_t)g * N + n0 + c];
  const float zp = zer[(size_t)g * N + n0 + c];
#pragma unroll
  for (int i = 0; i < 8; ++i) {
    const int k = i * 8 + rp * 2;
    const float q0 = (float)W[(size_t)(k0 + k) * N + n0 + c];
    const float q1 = (float)W[(size_t)(k0 + k + 1) * N + n0 + c];
    half2v p;
    p[0] = (_Float16)((q0 - zp) * sc);
    p[1] = (_Float16)((q1 - zp) * sc);
    *(half2v*)&lT[c * 84 + k] = p;
  }
  __syncthreads();
  const int kc = tid & 7, nr0 = tid >> 3;
#pragma unroll
  for (int i = 0; i < 2; ++i) {
    const int n = nr0 + 32 * i;
    union { half8v v8; half4v v4[2]; } u;
    u.v4[0] = *(const half4v*)&lT[n * 84 + kc * 8];
    u.v4[1] = *(const half4v*)&lT[n * 84 + kc * 8 + 4];
    *(half8v*)&Wt[(size_t)(n0 + n) * K + k0 + kc * 8] = u.v8;
  }
}

// ---------------- hidden f32 -> f16 ----------------
__global__ __launch_bounds__(256) void conv_a(const float* __restrict__ A, _Float16* __restrict__ Af) {
  const int i = blockIdx.x * 256 + threadIdx.x;
  const float4 t = ((const float4*)A)[i];
  half4v r;
  r[0] = (_Float16)t.x; r[1] = (_Float16)t.y; r[2] = (_Float16)t.z; r[3] = (_Float16)t.w;
  ((half4v*)Af)[i] = r;
}

// ---------------- staging helpers (512-thread blocks) ----------------
__device__ inline void stage128x64(const _Float16* __restrict__ gp, int K,
                                   _Float16* lp, int wave, int stR, int stC) {
  g2lds16(gp + (size_t)(wave * 16 + stR) * K + stC, lp + (wave * 2) * 512);
  g2lds16(gp + (size_t)(wave * 16 + 8 + stR) * K + stC, lp + (wave * 2 + 1) * 512);
}
__device__ inline void stage64x64(const _Float16* __restrict__ gp, int K,
                                  _Float16* lp, int wave, int stR, int stC) {
  g2lds16(gp + (size_t)(wave * 8 + stR) * K + stC, lp + wave * 512);
}

// ---------------- unified 2-phase single-barrier GEMM (round-8 proven @50% util) ----------
template <int NBF, typename CT>
__global__ __launch_bounds__(512, 2) void gemm_2ph(const _Float16* __restrict__ A,
                                                   const _Float16* __restrict__ Bt,
                                                   CT* __restrict__ C, int M, int N, int K) {
  __shared__ _Float16 sA[3][2][128 * 64];
  __shared__ _Float16 sB[2][NBF * 64 * 64];

  const int tid = threadIdx.x;
  const int wave = tid >> 6, lane = tid & 63;
  const int quad = lane >> 4, l16 = lane & 15;
  const int wr = wave >> 2;  // M half (128 rows)
  const int wc = wave & 3;   // N quarter (NBF*16 cols)
  const int NT = K >> 6;

  const _Float16* Ab = A + (size_t)(blockIdx.y * 256) * K;
  const _Float16* Bb = Bt + (size_t)(blockIdx.x * (NBF * 64)) * K;

  const int stR = lane >> 3;
  const int stC = ((lane & 7) ^ stR) << 3;
  const int fx = l16 & 7;

#define COFF(ks_) ((((ks_) * 4 + quad) ^ fx) << 3)
#define SYNC_MFMA()                                  \
  __builtin_amdgcn_s_barrier();                      \
  asm volatile("s_waitcnt lgkmcnt(0)" ::: "memory"); \
  __builtin_amdgcn_sched_barrier(0);

  f32x4 acc[8][NBF];
  const f32x4 zero4 = {0.f, 0.f, 0.f, 0.f};
#pragma unroll
  for (int m8 = 0; m8 < 8; ++m8)
#pragma unroll
    for (int nb = 0; nb < NBF; ++nb) acc[m8][nb] = zero4;

  // ---- prologue: B(0)[NBF], A(0)[4], A(1)[4]; vmcnt(4) leaves A(1) in flight ----
#pragma unroll
  for (int j = 0; j < NBF; ++j)
    stage64x64(Bb + (size_t)(j * 64) * K, K, &sB[0][j * 4096], wave, stR, stC);
  stage128x64(Ab, K, &sA[0][0][0], wave, stR, stC);
  stage128x64(Ab + (size_t)128 * K, K, &sA[0][1][0], wave, stR, stC);
  stage128x64(Ab + 64, K, &sA[1][0][0], wave, stR, stC);
  stage128x64(Ab + (size_t)128 * K + 64, K, &sA[1][1][0], wave, stR, stC);
  asm volatile("s_waitcnt vmcnt(4)" ::: "memory");
  __builtin_amdgcn_s_barrier();

  int bA = 0;  // = t % 3
  for (int t = 0; t < NT; ++t) {
    const int bB = t & 1;
    const int bA2 = (bA + 2 >= 3) ? bA - 1 : bA + 2;  // (t+2) % 3
    half8v af[4][2], bf[NBF][2];

    // ===== P1: a0 x all b =====
#pragma unroll
    for (int mb = 0; mb < 4; ++mb)
#pragma unroll
      for (int ks = 0; ks < 2; ++ks)
        af[mb][ks] = *(const half8v*)&sA[bA][wr][(mb * 16 + l16) * 64 + COFF(ks)];
#pragma unroll
    for (int nb = 0; nb < NBF; ++nb)
#pragma unroll
      for (int ks = 0; ks < 2; ++ks)
        bf[nb][ks] = *(const half8v*)&sB[bB][(wc * (NBF * 16) + nb * 16 + l16) * 64 + COFF(ks)];
    if (t + 1 < NT) {
#pragma unroll
      for (int j = 0; j < NBF; ++j)
        stage64x64(Bb + (size_t)(j * 64) * K + (size_t)(t + 1) * 64, K,
                   &sB[bB ^ 1][j * 4096], wave, stR, stC);
    }
    SYNC_MFMA()
    __builtin_amdgcn_s_setprio(1);
#pragma unroll
    for (int mb = 0; mb < 4; ++mb)
#pragma unroll
      for (int nb = 0; nb < NBF; ++nb)
#pragma unroll
        for (int ks = 0; ks < 2; ++ks)
          acc[mb][nb] =
              __builtin_amdgcn_mfma_f32_16x16x32_f16(af[mb][ks], bf[nb][ks], acc[mb][nb], 0, 0, 0);
    __builtin_amdgcn_s_setprio(0);

    // ===== P2: a1 x all b (bf reused) =====
#pragma unroll
    for (int mb = 0; mb < 4; ++mb)
#pragma unroll
      for (int ks = 0; ks < 2; ++ks)
        af[mb][ks] = *(const half8v*)&sA[bA][wr][(64 + mb * 16 + l16) * 64 + COFF(ks)];
    if (t + 2 < NT) {
      const _Float16* Ap = Ab + (size_t)(t + 2) * 64;
      stage128x64(Ap, K, &sA[bA2][0][0], wave, stR, stC);
      stage128x64(Ap + (size_t)128 * K, K, &sA[bA2][1][0], wave, stR, stC);
      asm volatile("s_waitcnt vmcnt(4)" ::: "memory");  // leaves exactly A(t+2) in flight
    } else if (t + 1 < NT) {
      asm volatile("s_waitcnt vmcnt(0)" ::: "memory");  // tail drain
    }
    SYNC_MFMA()
    __builtin_amdgcn_s_setprio(1);
#pragma unroll
    for (int mb = 0; mb < 4; ++mb)
#pragma unroll
      for (int nb = 0; nb < NBF; ++nb)
#pragma unroll
        for (int ks = 0; ks < 2; ++ks)
          acc[4 + mb][nb] = __builtin_amdgcn_mfma_f32_16x16x32_f16(af[mb][ks], bf[nb][ks],
                                                                   acc[4 + mb][nb], 0, 0, 0);
    __builtin_amdgcn_s_setprio(0);

    bA = (bA + 1 >= 3) ? 0 : bA + 1;
  }

  // ---- epilogue ----
  const int rbase = blockIdx.y * 256 + wr * 128 + quad * 4;
  const int cbase = blockIdx.x * (NBF * 64) + wc * (NBF * 16) + l16;
#pragma unroll
  for (int m8 = 0; m8 < 8; ++m8) {
    const int rowb = rbase + (m8 >> 2) * 64 + (m8 & 3) * 16;
#pragma unroll
    for (int nb = 0; nb < NBF; ++nb)
#pragma unroll
      for (int i = 0; i < 4; ++i)
        C[(size_t)(rowb + i) * N + cbase + nb * 16] = (CT)acc[m8][nb][i];
  }
#undef COFF
#undef SYNC_MFMA
}

// ---------------- RoPE on Q,K -> [h][s][d]; V -> Vt [h][d][s] ----------------
__global__ __launch_bounds__(256) void rope_kernel(const _Float16* __restrict__ proj,
                                                   const int* __restrict__ pos,
                                                   _Float16* __restrict__ Q, _Float16* __restrict__ K,
                                                   _Float16* __restrict__ Vt) {
  const int h = blockIdx.x, sb = blockIdx.y;
  const int tid = threadIdx.x;
  const int s0 = sb * 64;

#pragma unroll
  for (int it = 0; it < 16; ++it) {
    const int idx = it * 256 + tid;
    const int sl = idx >> 6, j = idx & 63;
    const int s = s0 + sl;
    const float p = (float)pos[s];
    const float invrev = exp2f(-0.20762050593045455f * (float)j) * 0.15915494309189535f;
    const float rev = p * invrev;
    const float frac = rev - floorf(rev);
    const float sn = __builtin_amdgcn_sinf(frac);
    const float cs = __builtin_amdgcn_cosf(frac);
    const _Float16* rp = proj + (size_t)s * NQKV + h * HD;
    {
      const float x1 = (float)rp[j], x2 = (float)rp[j + 64];
      _Float16* qp = Q + ((size_t)h * S_LEN + s) * HD;
      qp[j] = (_Float16)(x1 * cs - x2 * sn);
      qp[j + 64] = (_Float16)(x2 * cs + x1 * sn);
    }
    {
      const float x1 = (float)rp[HID_DIM + j], x2 = (float)rp[HID_DIM + j + 64];
      _Float16* kp = K + ((size_t)h * S_LEN + s) * HD;
      kp[j] = (_Float16)(x1 * cs - x2 * sn);
      kp[j + 64] = (_Float16)(x2 * cs + x1 * sn);
    }
  }

  __shared__ _Float16 lV[64 * 132];
#pragma unroll
  for (int r = 0; r < 4; ++r) {
    const int cid = r * 256 + tid;
    const int sl = cid >> 4;
    const int d0 = (cid & 15) * 8;
    const _Float16* vp = proj + (size_t)(s0 + sl) * NQKV + 2 * HID_DIM + h * HD + d0;
    *(half4v*)&lV[sl * 132 + d0] = *(const half4v*)vp;
    *(half4v*)&lV[sl * 132 + d0 + 4] = *(const half4v*)(vp + 4);
  }
  __syncthreads();
#pragma unroll
  for (int it = 0; it < 32; ++it) {
    const int d = it * 4 + (tid >> 6);
    const int sl = tid & 63;
    Vt[((size_t)h * HD + d) * S_LEN + s0 + sl] = lV[sl * 132 + d];
  }
}

// ---------------- flash attention: LDS-free K/V, barrier-free, per-wave independent ----------
// Key fact (verified by unwinding the old swizzle algebra end-to-end): the K/V fragments
// are WAVE-INVARIANT and map to clean global addresses:
//   kf[hf][c] = K[kt*32 + hf*16 + l16][c*32 + quad*8 .. +8]    (16B aligned)
//   vf[c]     = Vt[c*16 + l16][kt*32 + quad*8 .. +8]           (16B aligned)
// Per load instruction a wave touches 16 fully-consumed 64B lines -> L2-friendly; K/V per
// head = 1 MB, L2-resident and reused 16x by q-blocks (guide: don't LDS-stage what
// cache-fits). Dropping the staging removes ALL barriers and vmcnt choreography -> waves
// skew freely; 8 waves/CU hide L2 latency. Only LDS left: per-wave lP transpose
// (intra-wave, compiler-ordered via lgkmcnt).
__global__ __launch_bounds__(256, 2) void flash_attn(const _Float16* __restrict__ Q,
                                                     const _Float16* __restrict__ Km,
                                                     const _Float16* __restrict__ Vt,
                                                     _Float16* __restrict__ O) {
  __shared__ _Float16 lP[4][2][16 * 40];  // per-wave P staging
  const int h = blockIdx.y;
  const int xb = blockIdx.x;
  const int qb = (xb & 1) ? (15 - (xb >> 1)) : (xb >> 1);  // light/heavy pairing
  const int tid = threadIdx.x;
  const int wave = tid >> 6, lane = tid & 63;
  const int quad = lane >> 4, l16 = lane & 15;
  const int q0w = qb * 128 + wave * 32;
  const float scale = 0.08838834764831845f;

  const _Float16* Qh = Q + (size_t)h * S_LEN * HD;
  const _Float16* Kh = Km + (size_t)h * S_LEN * HD;
  const _Float16* Vh = Vt + (size_t)h * HD * S_LEN;

  half8v qf[2][4];
#pragma unroll
  for (int r = 0; r < 2; ++r)
#pragma unroll
    for (int c = 0; c < 4; ++c)
      qf[r][c] = *(const half8v*)&Qh[(size_t)(q0w + r * 16 + l16) * HD + c * 32 + quad * 8];

  const f32x4 zero4 = {0.f, 0.f, 0.f, 0.f};
  f32x4 o[2][8];
  f32x4 lp[2];
#pragma unroll
  for (int r = 0; r < 2; ++r) {
    lp[r] = zero4;
#pragma unroll
    for (int c = 0; c < 8; ++c) o[r][c] = zero4;
  }

  // per-lane fragment base pointers (advance per tile)
  const _Float16* kp = Kh + (size_t)l16 * HD + quad * 8;
  const _Float16* vp = Vh + (size_t)l16 * S_LEN + quad * 8;

  const int ntiles = 4 * qb + 4;
  for (int kt = 0; kt < ntiles; ++kt) {
    // ---- direct global->reg fragment loads (L2-served; no LDS, no barrier) ----
    half8v kf[2][4];
#pragma unroll
    for (int hf = 0; hf < 2; ++hf)
#pragma unroll
      for (int c = 0; c < 4; ++c)
        kf[hf][c] = *(const half8v*)(kp + (size_t)(kt * 32 + hf * 16) * HD + c * 32);
    half8v vf[8];
#pragma unroll
    for (int c = 0; c < 8; ++c)
      vf[c] = *(const half8v*)(vp + (size_t)(c * 16) * S_LEN + kt * 32);

    // ---- QK^T ----
    f32x4 s[2][2];
#pragma unroll
    for (int r = 0; r < 2; ++r)
#pragma unroll
      for (int hf = 0; hf < 2; ++hf) {
        s[r][hf] = zero4;
#pragma unroll
        for (int c = 0; c < 4; ++c)
          s[r][hf] = __builtin_amdgcn_mfma_f32_16x16x32_f16(qf[r][c], kf[hf][c], s[r][hf], 0, 0, 0);
      }

    // ---- exp + mask + P staging (per-wave LDS, intra-wave ordering) ----
#pragma unroll
    for (int r = 0; r < 2; ++r) {
      float p0[4], p1[4];
#pragma unroll
      for (int i = 0; i < 4; ++i) {
        const int row = q0w + r * 16 + quad * 4 + i;
        const int col0 = kt * 32 + l16, col1 = col0 + 16;
        const float e0 = __expf(s[r][0][i] * scale);
        const float e1 = __expf(s[r][1][i] * scale);
        p0[i] = (col0 <= row) ? e0 : 0.f;
        p1[i] = (col1 <= row) ? e1 : 0.f;
        lp[r][i] += p0[i] + p1[i];
      }
      _Float16* pw = lP[wave][r];
#pragma unroll
      for (int i = 0; i < 4; ++i) {
        pw[(quad * 4 + i) * 40 + l16] = (_Float16)p0[i];
        pw[(quad * 4 + i) * 40 + l16 + 16] = (_Float16)p1[i];
      }
    }
    half8v pa[2];
#pragma unroll
    for (int r = 0; r < 2; ++r) pa[r] = *(half8v*)&lP[wave][r][l16 * 40 + quad * 8];

    // ---- PV ----
#pragma unroll
    for (int c = 0; c < 8; ++c)
#pragma unroll
      for (int r = 0; r < 2; ++r)
        o[r][c] = __builtin_amdgcn_mfma_f32_16x16x32_f16(pa[r], vf[c], o[r][c], 0, 0, 0);
  }

#pragma unroll
  for (int r = 0; r < 2; ++r) {
    f32x4 ls = lp[r];
#pragma unroll
    for (int off = 1; off < 16; off <<= 1) {
#pragma unroll
      for (int i = 0; i < 4; ++i) ls[i] += __shfl_xor(ls[i], off);
    }
    f32x4 inv;
#pragma unroll
    for (int i = 0; i < 4; ++i) inv[i] = 1.f / ls[i];
#pragma unroll
    for (int c = 0; c < 8; ++c) {
#pragma unroll
      for (int i = 0; i < 4; ++i) {
        const int row = q0w + r * 16 + quad * 4 + i;
        O[(size_t)row * HID_DIM + h * HD + c * 16 + l16] = (_Float16)(o[r][c][i] * inv[i]);
      }
    }
  }
}

extern "C" void kernel_launch(void* const* d_in, const int* in_sizes, int n_in,
                              void* d_out, int out_size, void* d_ws, size_t ws_size,
                              hipStream_t stream) {
  const float* hidden = (const float*)d_in[0];
  const int* pos = (const int*)d_in[1];
  const int* qkv_w = (const int*)d_in[2];
  const float* qkv_s = (const float*)d_in[3];
  const float* qkv_z = (const float*)d_in[4];
  const int* o_w = (const int*)d_in[5];
  const float* o_s = (const float*)d_in[6];
  const float* o_z = (const float*)d_in[7];

  // workspace overlays (160 MiB total)
  char* ws = (char*)d_ws;
  _Float16* Wt_qkv = (_Float16*)(ws + 0);
  _Float16* Qb = (_Float16*)(ws + 0);
  _Float16* Kb = (_Float16*)(ws + 16777216);
  _Float16* Vtb = (_Float16*)(ws + 33554432);
  _Float16* Af16 = (_Float16*)(ws + 100663296);
  _Float16* attn = (_Float16*)(ws + 100663296);
  _Float16* proj = (_Float16*)(ws + 117440512);
  _Float16* Wt_o = (_Float16*)(ws + 117440512);
  float* out = (float*)d_out;

  hipLaunchKernelGGL(dequant_w, dim3(192, 64), dim3(256), 0, stream,
                     qkv_w, qkv_s, qkv_z, Wt_qkv, 4096, 12288);
  hipLaunchKernelGGL(conv_a, dim3(8192), dim3(256), 0, stream, hidden, Af16);
  hipLaunchKernelGGL((gemm_2ph<3, _Float16>), dim3(64, 8), dim3(512), 0, stream,
                     Af16, Wt_qkv, proj, 2048, 12288, 4096);
  hipLaunchKernelGGL(rope_kernel, dim3(32, 32), dim3(256), 0, stream, proj, pos, Qb, Kb, Vtb);
  hipLaunchKernelGGL(dequant_w, dim3(64, 64), dim3(256), 0, stream,
                     o_w, o_s, o_z, Wt_o, 4096, 4096);
  hipLaunchKernelGGL(flash_attn, dim3(16, 32), dim3(256), 0, stream, Qb, Kb, Vtb, attn);
  hipLaunchKernelGGL((gemm_2ph<2, float>), dim3(32, 8), dim3(512), 0, stream,
                     attn, Wt_o, out, 2048, 4096, 4096);
}

// Round 11
// 716.234 us; speedup vs baseline: 1.1910x; 1.1910x over previous
//
#include <hip/hip_runtime.h>
#include <hip/hip_bf16.h>

#define S_LEN 2048
#define HID_DIM 4096
#define NH 32
#define HD 128
#define NQKV 12288

typedef _Float16 half2v __attribute__((ext_vector_type(2)));
typedef _Float16 half4v __attribute__((ext_vector_type(4)));
typedef _Float16 half8v __attribute__((ext_vector_type(8)));
typedef float f32x4 __attribute__((ext_vector_type(4)));

typedef const __attribute__((address_space(1))) unsigned int* gas_u32;
typedef __attribute__((address_space(3))) unsigned int* las_u32;

__device__ inline void g2lds16(const _Float16* g, _Float16* l) {
  __builtin_amdgcn_global_load_lds((gas_u32)g, (las_u32)l, 16, 0, 0);
}

// ---------------- dequant W[K,N] int32 -> Wt[N,K] f16 (transposed) ----------------
__global__ __launch_bounds__(256) void dequant_w(const int* __restrict__ W,
                                                 const float* __restrict__ scal,
                                                 const float* __restrict__ zer,
                                                 _Float16* __restrict__ Wt, int K, int N) {
  __shared__ _Float16 lT[64 * 84];  // [n][k]
  const int k0 = blockIdx.y * 64, n0 = blockIdx.x * 64;
  const int tid = threadIdx.x, c = tid & 63, rp = tid >> 6;
  const int g = k0 >> 7;  // 64 | 128 -> group uniform over tile
  const float sc = scal[(size_t)g * N + n0 + c];
  const float zp = zer[(size_t)g * N + n0 + c];
#pragma unroll
  for (int i = 0; i < 8; ++i) {
    const int k = i * 8 + rp * 2;
    const float q0 = (float)W[(size_t)(k0 + k) * N + n0 + c];
    const float q1 = (float)W[(size_t)(k0 + k + 1) * N + n0 + c];
    half2v p;
    p[0] = (_Float16)((q0 - zp) * sc);
    p[1] = (_Float16)((q1 - zp) * sc);
    *(half2v*)&lT[c * 84 + k] = p;
  }
  __syncthreads();
  const int kc = tid & 7, nr0 = tid >> 3;
#pragma unroll
  for (int i = 0; i < 2; ++i) {
    const int n = nr0 + 32 * i;
    union { half8v v8; half4v v4[2]; } u;
    u.v4[0] = *(const half4v*)&lT[n * 84 + kc * 8];
    u.v4[1] = *(const half4v*)&lT[n * 84 + kc * 8 + 4];
    *(half8v*)&Wt[(size_t)(n0 + n) * K + k0 + kc * 8] = u.v8;
  }
}

// ---------------- hidden f32 -> f16 ----------------
__global__ __launch_bounds__(256) void conv_a(const float* __restrict__ A, _Float16* __restrict__ Af) {
  const int i = blockIdx.x * 256 + threadIdx.x;
  const float4 t = ((const float4*)A)[i];
  half4v r;
  r[0] = (_Float16)t.x; r[1] = (_Float16)t.y; r[2] = (_Float16)t.z; r[3] = (_Float16)t.w;
  ((half4v*)Af)[i] = r;
}

// ---------------- staging helpers (512-thread blocks) ----------------
__device__ inline void stage128x64(const _Float16* __restrict__ gp, int K,
                                   _Float16* lp, int wave, int stR, int stC) {
  g2lds16(gp + (size_t)(wave * 16 + stR) * K + stC, lp + (wave * 2) * 512);
  g2lds16(gp + (size_t)(wave * 16 + 8 + stR) * K + stC, lp + (wave * 2 + 1) * 512);
}
__device__ inline void stage64x64(const _Float16* __restrict__ gp, int K,
                                  _Float16* lp, int wave, int stR, int stC) {
  g2lds16(gp + (size_t)(wave * 8 + stR) * K + stC, lp + wave * 512);
}

// ---------------- unified 2-phase single-barrier GEMM (round-8 proven @50% util) ----------
template <int NBF, typename CT>
__global__ __launch_bounds__(512, 2) void gemm_2ph(const _Float16* __restrict__ A,
                                                   const _Float16* __restrict__ Bt,
                                                   CT* __restrict__ C, int M, int N, int K) {
  __shared__ _Float16 sA[3][2][128 * 64];
  __shared__ _Float16 sB[2][NBF * 64 * 64];

  const int tid = threadIdx.x;
  const int wave = tid >> 6, lane = tid & 63;
  const int quad = lane >> 4, l16 = lane & 15;
  const int wr = wave >> 2;  // M half (128 rows)
  const int wc = wave & 3;   // N quarter (NBF*16 cols)
  const int NT = K >> 6;

  const _Float16* Ab = A + (size_t)(blockIdx.y * 256) * K;
  const _Float16* Bb = Bt + (size_t)(blockIdx.x * (NBF * 64)) * K;

  const int stR = lane >> 3;
  const int stC = ((lane & 7) ^ stR) << 3;
  const int fx = l16 & 7;

#define COFF(ks_) ((((ks_) * 4 + quad) ^ fx) << 3)
#define SYNC_MFMA()                                  \
  __builtin_amdgcn_s_barrier();                      \
  asm volatile("s_waitcnt lgkmcnt(0)" ::: "memory"); \
  __builtin_amdgcn_sched_barrier(0);

  f32x4 acc[8][NBF];
  const f32x4 zero4 = {0.f, 0.f, 0.f, 0.f};
#pragma unroll
  for (int m8 = 0; m8 < 8; ++m8)
#pragma unroll
    for (int nb = 0; nb < NBF; ++nb) acc[m8][nb] = zero4;

  // ---- prologue: B(0)[NBF], A(0)[4], A(1)[4]; vmcnt(4) leaves A(1) in flight ----
#pragma unroll
  for (int j = 0; j < NBF; ++j)
    stage64x64(Bb + (size_t)(j * 64) * K, K, &sB[0][j * 4096], wave, stR, stC);
  stage128x64(Ab, K, &sA[0][0][0], wave, stR, stC);
  stage128x64(Ab + (size_t)128 * K, K, &sA[0][1][0], wave, stR, stC);
  stage128x64(Ab + 64, K, &sA[1][0][0], wave, stR, stC);
  stage128x64(Ab + (size_t)128 * K + 64, K, &sA[1][1][0], wave, stR, stC);
  asm volatile("s_waitcnt vmcnt(4)" ::: "memory");
  __builtin_amdgcn_s_barrier();

  int bA = 0;  // = t % 3
  for (int t = 0; t < NT; ++t) {
    const int bB = t & 1;
    const int bA2 = (bA + 2 >= 3) ? bA - 1 : bA + 2;  // (t+2) % 3
    half8v af[4][2], bf[NBF][2];

    // ===== P1: a0 x all b =====
#pragma unroll
    for (int mb = 0; mb < 4; ++mb)
#pragma unroll
      for (int ks = 0; ks < 2; ++ks)
        af[mb][ks] = *(const half8v*)&sA[bA][wr][(mb * 16 + l16) * 64 + COFF(ks)];
#pragma unroll
    for (int nb = 0; nb < NBF; ++nb)
#pragma unroll
      for (int ks = 0; ks < 2; ++ks)
        bf[nb][ks] = *(const half8v*)&sB[bB][(wc * (NBF * 16) + nb * 16 + l16) * 64 + COFF(ks)];
    if (t + 1 < NT) {
#pragma unroll
      for (int j = 0; j < NBF; ++j)
        stage64x64(Bb + (size_t)(j * 64) * K + (size_t)(t + 1) * 64, K,
                   &sB[bB ^ 1][j * 4096], wave, stR, stC);
    }
    SYNC_MFMA()
    __builtin_amdgcn_s_setprio(1);
#pragma unroll
    for (int mb = 0; mb < 4; ++mb)
#pragma unroll
      for (int nb = 0; nb < NBF; ++nb)
#pragma unroll
        for (int ks = 0; ks < 2; ++ks)
          acc[mb][nb] =
              __builtin_amdgcn_mfma_f32_16x16x32_f16(af[mb][ks], bf[nb][ks], acc[mb][nb], 0, 0, 0);
    __builtin_amdgcn_s_setprio(0);

    // ===== P2: a1 x all b (bf reused) =====
#pragma unroll
    for (int mb = 0; mb < 4; ++mb)
#pragma unroll
      for (int ks = 0; ks < 2; ++ks)
        af[mb][ks] = *(const half8v*)&sA[bA][wr][(64 + mb * 16 + l16) * 64 + COFF(ks)];
    if (t + 2 < NT) {
      const _Float16* Ap = Ab + (size_t)(t + 2) * 64;
      stage128x64(Ap, K, &sA[bA2][0][0], wave, stR, stC);
      stage128x64(Ap + (size_t)128 * K, K, &sA[bA2][1][0], wave, stR, stC);
      asm volatile("s_waitcnt vmcnt(4)" ::: "memory");  // leaves exactly A(t+2) in flight
    } else if (t + 1 < NT) {
      asm volatile("s_waitcnt vmcnt(0)" ::: "memory");  // tail drain
    }
    SYNC_MFMA()
    __builtin_amdgcn_s_setprio(1);
#pragma unroll
    for (int mb = 0; mb < 4; ++mb)
#pragma unroll
      for (int nb = 0; nb < NBF; ++nb)
#pragma unroll
        for (int ks = 0; ks < 2; ++ks)
          acc[4 + mb][nb] = __builtin_amdgcn_mfma_f32_16x16x32_f16(af[mb][ks], bf[nb][ks],
                                                                   acc[4 + mb][nb], 0, 0, 0);
    __builtin_amdgcn_s_setprio(0);

    bA = (bA + 1 >= 3) ? 0 : bA + 1;
  }

  // ---- epilogue ----
  const int rbase = blockIdx.y * 256 + wr * 128 + quad * 4;
  const int cbase = blockIdx.x * (NBF * 64) + wc * (NBF * 16) + l16;
#pragma unroll
  for (int m8 = 0; m8 < 8; ++m8) {
    const int rowb = rbase + (m8 >> 2) * 64 + (m8 & 3) * 16;
#pragma unroll
    for (int nb = 0; nb < NBF; ++nb)
#pragma unroll
      for (int i = 0; i < 4; ++i)
        C[(size_t)(rowb + i) * N + cbase + nb * 16] = (CT)acc[m8][nb][i];
  }
#undef COFF
#undef SYNC_MFMA
}

// ---------------- RoPE on Q,K -> [h][s][d]; V -> Vt [h][d][s] ----------------
__global__ __launch_bounds__(256) void rope_kernel(const _Float16* __restrict__ proj,
                                                   const int* __restrict__ pos,
                                                   _Float16* __restrict__ Q, _Float16* __restrict__ K,
                                                   _Float16* __restrict__ Vt) {
  const int h = blockIdx.x, sb = blockIdx.y;
  const int tid = threadIdx.x;
  const int s0 = sb * 64;

#pragma unroll
  for (int it = 0; it < 16; ++it) {
    const int idx = it * 256 + tid;
    const int sl = idx >> 6, j = idx & 63;
    const int s = s0 + sl;
    const float p = (float)pos[s];
    const float invrev = exp2f(-0.20762050593045455f * (float)j) * 0.15915494309189535f;
    const float rev = p * invrev;
    const float frac = rev - floorf(rev);
    const float sn = __builtin_amdgcn_sinf(frac);
    const float cs = __builtin_amdgcn_cosf(frac);
    const _Float16* rp = proj + (size_t)s * NQKV + h * HD;
    {
      const float x1 = (float)rp[j], x2 = (float)rp[j + 64];
      _Float16* qp = Q + ((size_t)h * S_LEN + s) * HD;
      qp[j] = (_Float16)(x1 * cs - x2 * sn);
      qp[j + 64] = (_Float16)(x2 * cs + x1 * sn);
    }
    {
      const float x1 = (float)rp[HID_DIM + j], x2 = (float)rp[HID_DIM + j + 64];
      _Float16* kp = K + ((size_t)h * S_LEN + s) * HD;
      kp[j] = (_Float16)(x1 * cs - x2 * sn);
      kp[j + 64] = (_Float16)(x2 * cs + x1 * sn);
    }
  }

  __shared__ _Float16 lV[64 * 132];
#pragma unroll
  for (int r = 0; r < 4; ++r) {
    const int cid = r * 256 + tid;
    const int sl = cid >> 4;
    const int d0 = (cid & 15) * 8;
    const _Float16* vp = proj + (size_t)(s0 + sl) * NQKV + 2 * HID_DIM + h * HD + d0;
    *(half4v*)&lV[sl * 132 + d0] = *(const half4v*)vp;
    *(half4v*)&lV[sl * 132 + d0 + 4] = *(const half4v*)(vp + 4);
  }
  __syncthreads();
#pragma unroll
  for (int it = 0; it < 32; ++it) {
    const int d = it * 4 + (tid >> 6);
    const int sl = tid & 63;
    Vt[((size_t)h * HD + d) * S_LEN + s0 + sl] = lV[sl * 132 + d];
  }
}

// ---------------- flash attention: 4-deep K/V pipeline, prefetch distance 2 ----------------
// (round-9 proven version, reverted after round-10's LDS-free regression: fragment-layout
// global loads are inherently uncoalesced (16x64B segments/instr) and the barrier-free
// chain exposed full L2 latency at ~2 waves/SIMD -> 6% MfmaUtil. The g2lds pipeline
// keeps loads coalesced and 2 tiles in flight.)
__global__ __launch_bounds__(256) void flash_attn(const _Float16* __restrict__ Q,
                                                  const _Float16* __restrict__ Km,
                                                  const _Float16* __restrict__ Vt,
                                                  _Float16* __restrict__ O) {
  __shared__ _Float16 lK[4][32 * 128];    // [s][d], 16B slot s' = chunk ^ (row&15)
  __shared__ _Float16 lV[4][128 * 32];    // [d][s], 16B slot s' = chunk ^ ((row>>1)&3)
  __shared__ _Float16 lP[4][2][16 * 40];  // per-wave P staging
  const int h = blockIdx.y;
  const int xb = blockIdx.x;
  const int qb = (xb & 1) ? (15 - (xb >> 1)) : (xb >> 1);  // light/heavy pairing
  const int tid = threadIdx.x;
  const int wave = tid >> 6, lane = tid & 63;
  const int quad = lane >> 4, l16 = lane & 15;
  const int q0w = qb * 128 + wave * 32;
  const float scale = 0.08838834764831845f;

  const _Float16* Qh = Q + (size_t)h * S_LEN * HD;
  const _Float16* Kh = Km + (size_t)h * S_LEN * HD;
  const _Float16* Vh = Vt + (size_t)h * HD * S_LEN;

  const int kRow0 = wave * 8 + (lane >> 4);
  const int kSlot = lane & 15;
  const int vRow0 = wave * 32 + (lane >> 2);
  const int vSlot = lane & 3;

  auto stage_kv = [&](int kt_, int buf_) {
#pragma unroll
    for (int i = 0; i < 2; ++i) {
      const int row = kRow0 + i * 4;
      const int ck = kSlot ^ (row & 15);
      g2lds16(Kh + (size_t)(kt_ * 32 + row) * HD + ck * 8, &lK[buf_][(wave * 8 + i * 4) * 128]);
    }
#pragma unroll
    for (int i = 0; i < 2; ++i) {
      const int row = vRow0 + i * 16;
      const int cv = vSlot ^ ((row >> 1) & 3);
      g2lds16(Vh + (size_t)row * S_LEN + kt_ * 32 + cv * 8, &lV[buf_][(wave * 32 + i * 16) * 32]);
    }
  };

  half8v qf[2][4];
#pragma unroll
  for (int r = 0; r < 2; ++r)
#pragma unroll
    for (int c = 0; c < 4; ++c)
      qf[r][c] = *(const half8v*)&Qh[(size_t)(q0w + r * 16 + l16) * HD + c * 32 + quad * 8];

  const f32x4 zero4 = {0.f, 0.f, 0.f, 0.f};
  f32x4 o[2][8];
  f32x4 lp[2];
#pragma unroll
  for (int r = 0; r < 2; ++r) {
    lp[r] = zero4;
#pragma unroll
    for (int c = 0; c < 8; ++c) o[r][c] = zero4;
  }

  const int ntiles = 4 * qb + 4;  // uniform per block (>= 4)
  stage_kv(0, 0);
  stage_kv(1, 1);

  for (int kt = 0; kt < ntiles; ++kt) {
    const int cb = kt & 3;
    if (kt + 2 < ntiles) {
      stage_kv(kt + 2, (kt + 2) & 3);
      asm volatile("s_waitcnt vmcnt(8)" ::: "memory");  // drains s(kt); keeps s(kt+1),s(kt+2)
    } else if (kt + 1 < ntiles) {
      asm volatile("s_waitcnt vmcnt(4)" ::: "memory");  // drains s(kt); keeps s(kt+1)
    } else {
      asm volatile("s_waitcnt vmcnt(0)" ::: "memory");  // last tile: full drain
    }
    __builtin_amdgcn_s_barrier();

    half8v kf[2][4];
#pragma unroll
    for (int hf = 0; hf < 2; ++hf)
#pragma unroll
      for (int c = 0; c < 4; ++c) {
        const int slot = (c * 4 + quad) ^ l16;
        kf[hf][c] = *(const half8v*)&lK[cb][(hf * 16 + l16) * 128 + slot * 8];
      }
    half8v vf[8];
#pragma unroll
    for (int c = 0; c < 8; ++c) {
      const int slot = quad ^ ((l16 >> 1) & 3);
      vf[c] = *(const half8v*)&lV[cb][(c * 16 + l16) * 32 + slot * 8];
    }

    f32x4 s[2][2];
#pragma unroll
    for (int r = 0; r < 2; ++r)
#pragma unroll
      for (int hf = 0; hf < 2; ++hf) {
        s[r][hf] = zero4;
#pragma unroll
        for (int c = 0; c < 4; ++c)
          s[r][hf] = __builtin_amdgcn_mfma_f32_16x16x32_f16(qf[r][c], kf[hf][c], s[r][hf], 0, 0, 0);
      }

#pragma unroll
    for (int r = 0; r < 2; ++r) {
      float p0[4], p1[4];
#pragma unroll
      for (int i = 0; i < 4; ++i) {
        const int row = q0w + r * 16 + quad * 4 + i;
        const int col0 = kt * 32 + l16, col1 = col0 + 16;
        const float e0 = __expf(s[r][0][i] * scale);
        const float e1 = __expf(s[r][1][i] * scale);
        p0[i] = (col0 <= row) ? e0 : 0.f;
        p1[i] = (col1 <= row) ? e1 : 0.f;
        lp[r][i] += p0[i] + p1[i];
      }
      _Float16* pw = lP[wave][r];
#pragma unroll
      for (int i = 0; i < 4; ++i) {
        pw[(quad * 4 + i) * 40 + l16] = (_Float16)p0[i];
        pw[(quad * 4 + i) * 40 + l16 + 16] = (_Float16)p1[i];
      }
    }
    half8v pa[2];
#pragma unroll
    for (int r = 0; r < 2; ++r) pa[r] = *(half8v*)&lP[wave][r][l16 * 40 + quad * 8];

#pragma unroll
    for (int c = 0; c < 8; ++c)
#pragma unroll
      for (int r = 0; r < 2; ++r)
        o[r][c] = __builtin_amdgcn_mfma_f32_16x16x32_f16(pa[r], vf[c], o[r][c], 0, 0, 0);
  }

#pragma unroll
  for (int r = 0; r < 2; ++r) {
    f32x4 ls = lp[r];
#pragma unroll
    for (int off = 1; off < 16; off <<= 1) {
#pragma unroll
      for (int i = 0; i < 4; ++i) ls[i] += __shfl_xor(ls[i], off);
    }
    f32x4 inv;
#pragma unroll
    for (int i = 0; i < 4; ++i) inv[i] = 1.f / ls[i];
#pragma unroll
    for (int c = 0; c < 8; ++c) {
#pragma unroll
      for (int i = 0; i < 4; ++i) {
        const int row = q0w + r * 16 + quad * 4 + i;
        O[(size_t)row * HID_DIM + h * HD + c * 16 + l16] = (_Float16)(o[r][c][i] * inv[i]);
      }
    }
  }
}

extern "C" void kernel_launch(void* const* d_in, const int* in_sizes, int n_in,
                              void* d_out, int out_size, void* d_ws, size_t ws_size,
                              hipStream_t stream) {
  const float* hidden = (const float*)d_in[0];
  const int* pos = (const int*)d_in[1];
  const int* qkv_w = (const int*)d_in[2];
  const float* qkv_s = (const float*)d_in[3];
  const float* qkv_z = (const float*)d_in[4];
  const int* o_w = (const int*)d_in[5];
  const float* o_s = (const float*)d_in[6];
  const float* o_z = (const float*)d_in[7];

  // workspace overlays (160 MiB total)
  char* ws = (char*)d_ws;
  _Float16* Wt_qkv = (_Float16*)(ws + 0);
  _Float16* Qb = (_Float16*)(ws + 0);
  _Float16* Kb = (_Float16*)(ws + 16777216);
  _Float16* Vtb = (_Float16*)(ws + 33554432);
  _Float16* Af16 = (_Float16*)(ws + 100663296);
  _Float16* attn = (_Float16*)(ws + 100663296);
  _Float16* proj = (_Float16*)(ws + 117440512);
  _Float16* Wt_o = (_Float16*)(ws + 117440512);
  float* out = (float*)d_out;

  hipLaunchKernelGGL(dequant_w, dim3(192, 64), dim3(256), 0, stream,
                     qkv_w, qkv_s, qkv_z, Wt_qkv, 4096, 12288);
  hipLaunchKernelGGL(conv_a, dim3(8192), dim3(256), 0, stream, hidden, Af16);
  hipLaunchKernelGGL((gemm_2ph<3, _Float16>), dim3(64, 8), dim3(512), 0, stream,
                     Af16, Wt_qkv, proj, 2048, 12288, 4096);
  hipLaunchKernelGGL(rope_kernel, dim3(32, 32), dim3(256), 0, stream, proj, pos, Qb, Kb, Vtb);
  hipLaunchKernelGGL(dequant_w, dim3(64, 64), dim3(256), 0, stream,
                     o_w, o_s, o_z, Wt_o, 4096, 4096);
  hipLaunchKernelGGL(flash_attn, dim3(16, 32), dim3(256), 0, stream, Qb, Kb, Vtb, attn);
  hipLaunchKernelGGL((gemm_2ph<2, float>), dim3(32, 8), dim3(512), 0, stream,
                     attn, Wt_o, out, 2048, 4096, 4096);
}